// Round 4
// baseline (752.604 us; speedup 1.0000x reference)
//
#include <hip/hip_runtime.h>
#include <hip/hip_bf16.h>

#define TT 2048
#define BB 16
#define DD 1024
#define BD (BB*DD)          // 16384 cols per time row
#define MR (TT*BB)          // 32768 GEMM rows
#define EPSV 1e-6f
#define INVD (1.0f/1024.0f)
#define CH 256              // phase-B chunk length
#define NCH (TT/CH)         // 8
#define PH 8                // phase-A steps per barrier phase
#define NPH (TT/PH)         // 256
#define NGP (NPH+2)         // 258

typedef __bf16 bf16x8_t __attribute__((ext_vector_type(8)));
typedef float  f32x4_t  __attribute__((ext_vector_type(4)));
typedef float  f32x2    __attribute__((ext_vector_type(2)));
typedef __attribute__((address_space(1))) void gvoid_t;
typedef __attribute__((address_space(3))) void lvoid_t;

union F4 { float4 v; f32x2 h[2]; float f[4]; };

static __device__ __forceinline__ f32x2 pk_mul(f32x2 a, f32x2 b) {
    f32x2 d; asm("v_pk_mul_f32 %0, %1, %2" : "=v"(d) : "v"(a), "v"(b)); return d;
}
static __device__ __forceinline__ f32x2 pk_fma(f32x2 a, f32x2 b, f32x2 c) {
    f32x2 d; asm("v_pk_fma_f32 %0, %1, %2, %3" : "=v"(d) : "v"(a), "v"(b), "v"(c)); return d;
}
static __device__ __forceinline__ f32x2 pk_add(f32x2 a, f32x2 b) {
    f32x2 d; asm("v_pk_add_f32 %0, %1, %2" : "=v"(d) : "v"(a), "v"(b)); return d;
}
// wave64 DPP sum -> total in lane 63 -> broadcast via readlane (verified v2/v3)
static __device__ __forceinline__ float wave_red_sum(float ss) {
    asm volatile(
        "s_nop 1\n\t"
        "v_add_f32 %0, %0, %0 row_shr:1 bound_ctrl:0\n\t"
        "s_nop 1\n\t"
        "v_add_f32 %0, %0, %0 row_shr:2 bound_ctrl:0\n\t"
        "s_nop 1\n\t"
        "v_add_f32 %0, %0, %0 row_shr:4 bank_mask:0xe\n\t"
        "s_nop 1\n\t"
        "v_add_f32 %0, %0, %0 row_shr:8 bank_mask:0xc\n\t"
        "s_nop 1\n\t"
        "v_add_f32 %0, %0, %0 row_bcast:15 row_mask:0xa\n\t"
        "s_nop 1\n\t"
        "v_add_f32 %0, %0, %0 row_bcast:31 row_mask:0xc\n\t"
        "s_nop 1"
        : "+v"(ss));
    return __builtin_bit_cast(float, __builtin_amdgcn_readlane(__builtin_bit_cast(int, ss), 63));
}

static __device__ __forceinline__ unsigned short f2bf(float f) {
    __hip_bfloat16 h = __float2bfloat16(f);
    return __builtin_bit_cast(unsigned short, h);
}

// ---------------------------------------------------------------------------
// K0: convert x and W to bf16 (unchanged)
// ---------------------------------------------------------------------------
__global__ void k_convert(const float* __restrict__ x, const float* __restrict__ W,
                          unsigned short* __restrict__ xb, unsigned short* __restrict__ wb) {
    const long NX4 = (long)MR * DD / 4;
    const long NW4 = (long)DD * DD / 4;
    const long stride = (long)gridDim.x * blockDim.x;
    for (long j = (long)blockIdx.x * blockDim.x + threadIdx.x; j < NX4 + NW4; j += stride) {
        const float4* src; unsigned short* dst; long o;
        if (j < NX4) { src = (const float4*)x; dst = xb; o = j; }
        else         { src = (const float4*)W; dst = wb; o = j - NX4; }
        float4 v = src[o];
        ushort4 u;
        u.x = f2bf(v.x); u.y = f2bf(v.y); u.z = f2bf(v.z); u.w = f2bf(v.w);
        *(ushort4*)(dst + o * 4) = u;
    }
}

// ---------------------------------------------------------------------------
// K1: Wx = x @ W^T + b  (bf16 MFMA). Unchanged.
// ---------------------------------------------------------------------------
__global__ __launch_bounds__(256, 2)
void k_gemm(const unsigned short* __restrict__ A, const unsigned short* __restrict__ Bw,
            const float* __restrict__ bias, float* __restrict__ C) {
    __shared__ char lds[16384];
    char* ldsA = lds;
    char* ldsB = lds + 8192;
    const int tid  = threadIdx.x;
    const int lane = tid & 63;
    const int wid  = tid >> 6;
    const int wm = wid >> 1, wn = wid & 1;
    const size_t arow0 = (size_t)blockIdx.y * 128;
    const int    brow0 = blockIdx.x * 128;

    f32x4_t acc[4][4] = {};

    const int off0 = tid * 16,        row0_ = off0 >> 6, colb0 = off0 & 63;
    const int off1 = 4096 + tid * 16, row1_ = off1 >> 6, colb1 = off1 & 63;

    for (int kk = 0; kk < DD / 32; ++kk) {
        const int kbase = kk * 32;
        __builtin_amdgcn_global_load_lds(
            (gvoid_t*)(A + (arow0 + row0_) * DD + kbase + (colb0 >> 1)),
            (lvoid_t*)(ldsA + off0), 16, 0, 0);
        __builtin_amdgcn_global_load_lds(
            (gvoid_t*)(A + (arow0 + row1_) * DD + kbase + (colb1 >> 1)),
            (lvoid_t*)(ldsA + off1), 16, 0, 0);
        __builtin_amdgcn_global_load_lds(
            (gvoid_t*)(Bw + (size_t)(brow0 + row0_) * DD + kbase + (colb0 >> 1)),
            (lvoid_t*)(ldsB + off0), 16, 0, 0);
        __builtin_amdgcn_global_load_lds(
            (gvoid_t*)(Bw + (size_t)(brow0 + row1_) * DD + kbase + (colb1 >> 1)),
            (lvoid_t*)(ldsB + off1), 16, 0, 0);
        __syncthreads();

        const int ml = lane & 15;
        const int kh = (lane >> 4) * 16;
        bf16x8_t av[4], bv[4];
        #pragma unroll
        for (int i = 0; i < 4; ++i) {
            av[i] = *(const bf16x8_t*)(ldsA + (wm * 64 + i * 16 + ml) * 64 + kh);
            bv[i] = *(const bf16x8_t*)(ldsB + (wn * 64 + i * 16 + ml) * 64 + kh);
        }
        #pragma unroll
        for (int i = 0; i < 4; ++i)
            #pragma unroll
            for (int j = 0; j < 4; ++j)
                acc[i][j] = __builtin_amdgcn_mfma_f32_16x16x32_bf16(av[i], bv[j], acc[i][j], 0, 0, 0);
        __syncthreads();
    }

    const int rq = (lane >> 4) * 4;
    const int cl = lane & 15;
    #pragma unroll
    for (int i = 0; i < 4; ++i) {
        #pragma unroll
        for (int j = 0; j < 4; ++j) {
            const int n = brow0 + wn * 64 + j * 16 + cl;
            const float bb = bias[n];
            #pragma unroll
            for (int q = 0; q < 4; ++q) {
                const size_t m = arow0 + wm * 64 + i * 16 + rq + q;
                C[m * DD + n] = acc[i][j][q] + bb;
            }
        }
    }
}

// ---------------------------------------------------------------------------
// K2: phase A v4 — 3 waves/block.
// V (wave 0): sequential scan with the ss-recurrence; the wave reduction
//   (e = dot(hraw, w)) has a 2-iteration lead and is OFF the scalar chain.
// H1/H2 (waves 1,2): stage Wx rows into a 32-row LDS ring via
//   global_load_lds (counted vmcnt(16) before barrier -> never drains fresh
//   DMAs) and produce the data-only tables G[t]=a^2*dot(w_t,w_{t+1}),
//   Q[t]=a^2*sum(w_t^2).
// Phase pipeline: H DMAs set gp+1, computes GQ for set gp-1; V consumes
//   block gp-2. Ring distance analysis mod 32: no collisions.
// ---------------------------------------------------------------------------
__global__ __launch_bounds__(192, 1)
void k_phaseA(const float* __restrict__ Wx, const float* __restrict__ h0,
              const float* __restrict__ la, float* __restrict__ hout,
              float* __restrict__ rtab) {
    __shared__ float  ring[32 * DD];   // 128 KB
    __shared__ float2 gqtab[TT];       // 16 KB   idx t-1 -> {G_t, Q_t}
    __shared__ float  rbuf[TT];        // 8 KB

    const int b    = blockIdx.x;
    const int tid  = threadIdx.x;
    const int wid  = tid >> 6;
    const int lane = tid & 63;
    const int dof  = lane * 4;
    const float alpha = expf(la[0]);

    // ---- V state ----
    f32x2  hraw[8];
    F4     wU[2][4], wE[2][4];
    float  eEv[2] = {0.f, 0.f};
    float2 gq[2] = {};
    float  vr1 = 1.f, vr2 = 1.f, ss = 0.f;
    int    su = 2 * DD, se = 4 * DD;

    // ---- H pre-loop: DMA row set 0 (rows 0..7) ----
    if (wid > 0) {
        const int half = wid - 1;
        #pragma unroll
        for (int jj = 0; jj < 4; ++jj) {
            const int row = half * 4 + jj;
            #pragma unroll
            for (int k = 0; k < 4; ++k)
                __builtin_amdgcn_global_load_lds(
                    (gvoid_t*)(Wx + (size_t)row * BD + b * DD + k * 256 + dof),
                    (lvoid_t*)(ring + (row & 31) * DD + k * 256), 16, 0, 0);
        }
    }

    for (int gp = 0; gp < NGP; ++gp) {
        if (wid == 0) {
            // ================= V wave =================
            if (gp == 1) {
                // prologue: h0, rows 0..3, direct reductions
                #pragma unroll
                for (int k = 0; k < 4; ++k) {
                    F4 u; u.v = *(const float4*)(h0 + b * DD + k * 256 + dof);
                    hraw[2*k] = u.h[0]; hraw[2*k+1] = u.h[1];
                }
                F4 rw0[4], rw1[4], rw2[4], rw3[4];
                #pragma unroll
                for (int k = 0; k < 4; ++k) {
                    rw0[k].v = *(const float4*)(ring + 0 * DD + k * 256 + dof);
                    rw1[k].v = *(const float4*)(ring + 1 * DD + k * 256 + dof);
                    rw2[k].v = *(const float4*)(ring + 2 * DD + k * 256 + dof);
                    rw3[k].v = *(const float4*)(ring + 3 * DD + k * 256 + dof);
                }
                // ss0 = sum h0^2
                f32x2 sa = pk_mul(hraw[0], hraw[0]);
                #pragma unroll
                for (int p = 1; p < 8; ++p) sa = pk_fma(hraw[p], hraw[p], sa);
                ss = wave_red_sum(sa.x + sa.y);
                // D'_0 = a*dot(h0,row0) ; E'_1 = a*dot(h0,row1)
                f32x2 da = pk_mul(hraw[0], rw0[0].h[0]);
                f32x2 ea = pk_mul(hraw[0], rw1[0].h[0]);
                #pragma unroll
                for (int p = 1; p < 8; ++p) {
                    da = pk_fma(hraw[p], rw0[p>>1].h[p&1], da);
                    ea = pk_fma(hraw[p], rw1[p>>1].h[p&1], ea);
                }
                eEv[0] = alpha * wave_red_sum(da.x + da.y);
                eEv[1] = alpha * wave_red_sum(ea.x + ea.y);
                #pragma unroll
                for (int k = 0; k < 4; ++k) {
                    wU[0][k] = rw0[k]; wE[0][k] = rw2[k];
                    wU[1][k] = rw1[k]; wE[1][k] = rw3[k];
                }
                su = 2 * DD; se = 4 * DD; vr1 = 1.f; vr2 = 1.f;
            } else if (gp >= 2) {
                const int blk = gp - 2;
                if (blk == 0) {   // GQ idx 0..7 were written during phase 1
                    gq[0].x = 0.0f;        gq[0].y = gqtab[0].y;   // G_0:=0, Q_1
                    gq[1].x = gqtab[0].x;  gq[1].y = gqtab[1].y;   // G_1,   Q_2
                }
                #pragma unroll
                for (int s = 0; s < PH; ++s) {
                    const int t  = blk * PH + s + 1;
                    const int pe = s & 1;
                    // snapshot h_{t-1} (uses pre-update hraw, r_{t-1})
                    if (s == 0 && (blk & 31) == 0) {
                        float* hp = hout + (size_t)(t - 1) * BD + b * DD;
                        f32x2 rr0 = {vr1, vr1};
                        #pragma unroll
                        for (int k = 0; k < 4; ++k) {
                            F4 u;
                            u.h[0] = pk_mul(rr0, hraw[2*k]);
                            u.h[1] = pk_mul(rr0, hraw[2*k+1]);
                            *(float4*)(hp + k * 256 + dof) = u.v;
                        }
                    }
                    // ---- scalar chain (short): ss_t, r_t ----
                    const float Dp = fmaf(vr2, eEv[pe], gq[pe].x);
                    const float u1 = fmaf(vr1, ss, 2.0f * Dp);
                    ss = fmaf(vr1, u1, gq[pe].y);
                    const float ms = fmaf(ss, INVD, EPSV);
                    const float rt = __builtin_amdgcn_rsqf(ms);
                    if (lane == 0) rbuf[t - 1] = rt;
                    // ---- hraw_t = r_{t-1}*hraw_{t-1} + a*w_t ----
                    f32x2 rr1 = {vr1, vr1};
                    f32x2 aav = {alpha, alpha};
                    #pragma unroll
                    for (int p = 0; p < 8; ++p)
                        hraw[p] = pk_fma(rr1, hraw[p], pk_mul(aav, wU[pe][p>>1].h[p&1]));
                    // ---- e_{t+1} = dot(hraw_t, w_{t+2}) -> eEv[pe] (used at t+2) ----
                    f32x2 ea0 = pk_mul(hraw[0], wE[pe][0].h[0]);
                    f32x2 ea1 = pk_mul(hraw[1], wE[pe][0].h[1]);
                    f32x2 ea2 = pk_mul(hraw[2], wE[pe][1].h[0]);
                    f32x2 ea3 = pk_mul(hraw[3], wE[pe][1].h[1]);
                    ea0 = pk_fma(hraw[4], wE[pe][2].h[0], ea0);
                    ea1 = pk_fma(hraw[5], wE[pe][2].h[1], ea1);
                    ea2 = pk_fma(hraw[6], wE[pe][3].h[0], ea2);
                    ea3 = pk_fma(hraw[7], wE[pe][3].h[1], ea3);
                    ea0 = pk_add(ea0, ea1); ea2 = pk_add(ea2, ea3);
                    ea0 = pk_add(ea0, ea2);
                    eEv[pe] = alpha * wave_red_sum(ea0.x + ea0.y);
                    // ---- prefetch for iter t+2 ----
                    #pragma unroll
                    for (int k = 0; k < 4; ++k)
                        wU[pe][k].v = *(const float4*)(ring + su + k * 256 + dof);
                    #pragma unroll
                    for (int k = 0; k < 4; ++k)
                        wE[pe][k].v = *(const float4*)(ring + se + k * 256 + dof);
                    su = (su + DD) & (32 * DD - 1);
                    se = (se + DD) & (32 * DD - 1);
                    {
                        const int gi = (t     < TT - 1) ? t     : TT - 1;
                        const int qi = (t + 1 < TT - 1) ? t + 1 : TT - 1;
                        gq[pe].x = gqtab[gi].x;   // G_{t+1}
                        gq[pe].y = gqtab[qi].y;   // Q_{t+2}
                    }
                    // rotate r's
                    vr2 = vr1; vr1 = rt;
                }
            }
            __syncthreads();
        } else {
            // ================= H waves =================
            const int half = wid - 1;
            if (gp >= 1 && gp <= NPH) {
                const int sC = gp - 1;
                const int rbase = sC * PH + half * 4;
                F4 R[5][4];
                #pragma unroll
                for (int jj = 0; jj < 5; ++jj)
                    #pragma unroll
                    for (int k = 0; k < 4; ++k)
                        R[jj][k].v = *(const float4*)(ring + ((rbase + jj) & 31) * DD + k * 256 + dof);
                float red[8];
                #pragma unroll
                for (int sI = 0; sI < 4; ++sI) {
                    float g = 0.f, q = 0.f;
                    #pragma unroll
                    for (int k = 0; k < 4; ++k)
                        #pragma unroll
                        for (int j = 0; j < 4; ++j) {
                            const float w0 = R[sI][k].f[j], w1 = R[sI + 1][k].f[j];
                            g = fmaf(w0, w1, g);
                            q = fmaf(w0, w0, q);
                        }
                    red[sI] = g; red[4 + sI] = q;
                }
                #pragma unroll
                for (int m = 1; m < 64; m <<= 1)
                    #pragma unroll
                    for (int k = 0; k < 8; ++k)
                        red[k] += __shfl_xor(red[k], m, 64);
                if (lane == 0) {
                    const float a2 = alpha * alpha;
                    #pragma unroll
                    for (int sI = 0; sI < 4; ++sI)
                        gqtab[rbase + sI] = make_float2(a2 * red[sI], a2 * red[4 + sI]);
                }
            }
            if (gp < NPH - 1) {
                const int nb = (gp + 1) * PH + half * 4;
                #pragma unroll
                for (int jj = 0; jj < 4; ++jj) {
                    const int row = nb + jj;
                    #pragma unroll
                    for (int k = 0; k < 4; ++k)
                        __builtin_amdgcn_global_load_lds(
                            (gvoid_t*)(Wx + (size_t)row * BD + b * DD + k * 256 + dof),
                            (lvoid_t*)(ring + (row & 31) * DD + k * 256), 16, 0, 0);
                }
                // drain everything OLDER than this phase's 16 DMAs (free),
                // leave the fresh batch in flight across the barrier
                asm volatile("s_waitcnt vmcnt(16) lgkmcnt(0)" ::: "memory");
            } else {
                asm volatile("s_waitcnt vmcnt(0) lgkmcnt(0)" ::: "memory");
            }
            __builtin_amdgcn_s_barrier();
        }
    }

    // V: flush r-table to global
    if (wid == 0) {
        float* rrow = rtab + b * TT;
        #pragma unroll
        for (int i = 0; i < TT / 4 / 64; ++i) {
            const int j = (i * 64 + lane) * 4;
            *(float4*)(rrow + j) = *(const float4*)(rbuf + j);
        }
    }
}

// ---------------------------------------------------------------------------
// K3: phase B — parallel replay. Unchanged.
// ---------------------------------------------------------------------------
__global__ __launch_bounds__(256)
void k_phaseB(float* __restrict__ WxOut, float* __restrict__ hout,
              const float* __restrict__ rtab, const float* __restrict__ la) {
    const int col = blockIdx.x * 256 + threadIdx.x;
    const int c = blockIdx.y;
    const int b = col >> 10;
    const float alpha = expf(la[0]);
    const float* rr = rtab + b * TT;
    float h = hout[(size_t)(c * CH) * BD + col];
    const int t0 = c * CH + 1;
    float w = WxOut[(size_t)(t0 - 1) * BD + col];
    for (int s = 0; s < CH; ++s) {
        const int t = t0 + s;
        float wnext = 0.f;
        if (s + 1 < CH) wnext = WxOut[(size_t)t * BD + col];
        const float r = rr[t - 1];
        const float hraw = fmaf(alpha, w, h);
        const float hn = r * hraw;
        const float sg = 1.0f / (1.0f + __expf(-hn));
        WxOut[(size_t)(t - 1) * BD + col] = hn * hn * sg;
        if ((t & (CH - 1)) != 0 || t == TT)
            hout[(size_t)t * BD + col] = hn;
        h = hn;
        w = wnext;
    }
}

// ---------------------------------------------------------------------------
extern "C" void kernel_launch(void* const* d_in, const int* in_sizes, int n_in,
                              void* d_out, int out_size, void* d_ws, size_t ws_size,
                              hipStream_t stream) {
    (void)in_sizes; (void)n_in; (void)out_size; (void)ws_size;
    const float* x    = (const float*)d_in[0];
    const float* h0   = (const float*)d_in[1];
    const float* W    = (const float*)d_in[2];
    const float* bias = (const float*)d_in[3];
    const float* la   = (const float*)d_in[4];

    float* outr = (float*)d_out;                       // [T][B*D] : Wx, then out
    float* hreg = outr + (size_t)TT * BD;              // [T+1][B*D] : h output
    unsigned short* xb = (unsigned short*)hreg;        // bf16 x (dead space pre-phase-A)
    unsigned short* wb = xb + (size_t)MR * DD;         // bf16 W
    float* rtab = (float*)d_ws;                        // [B][T] = 128KB

    k_convert<<<2048, 256, 0, stream>>>(x, W, xb, wb);
    k_gemm<<<dim3(DD / 128, MR / 128), 256, 0, stream>>>(xb, wb, bias, outr);
    k_phaseA<<<BB, 192, 0, stream>>>(outr, h0, la, hreg, rtab);
    k_phaseB<<<dim3(BD / 256, NCH), 256, 0, stream>>>(outr, hreg, rtab, la);
}

// Round 6
// 579.310 us; speedup vs baseline: 1.2991x; 1.2991x over previous
//
#include <hip/hip_runtime.h>
#include <hip/hip_bf16.h>

#define TT 2048
#define BB 16
#define DD 1024
#define BD (BB*DD)          // 16384 cols per time row
#define MR (TT*BB)          // 32768 GEMM rows
#define EPSV 1e-6f
#define INVD (1.0f/1024.0f)
#define CH 256              // phase-B chunk length
#define NCH (TT/CH)         // 8
#define RING 16             // phase-A LDS ring depth (rows); 2048%16==0

typedef __bf16 bf16x8_t __attribute__((ext_vector_type(8)));
typedef float  f32x4_t  __attribute__((ext_vector_type(4)));
typedef float  f32x2    __attribute__((ext_vector_type(2)));
typedef __attribute__((address_space(1))) void gvoid_t;
typedef __attribute__((address_space(3))) void lvoid_t;
typedef __attribute__((address_space(3))) float  lds_f;
typedef __attribute__((address_space(3))) float2 lds_f2;

union F4 { f32x4_t q; float4 v; f32x2 h[2]; float f[4]; };

static __device__ __forceinline__ f32x2 pk_mul(f32x2 a, f32x2 b) {
    f32x2 d; asm("v_pk_mul_f32 %0, %1, %2" : "=v"(d) : "v"(a), "v"(b)); return d;
}
static __device__ __forceinline__ f32x2 pk_fma(f32x2 a, f32x2 b, f32x2 c) {
    f32x2 d; asm("v_pk_fma_f32 %0, %1, %2, %3" : "=v"(d) : "v"(a), "v"(b), "v"(c)); return d;
}
static __device__ __forceinline__ f32x2 pk_add(f32x2 a, f32x2 b) {
    f32x2 d; asm("v_pk_add_f32 %0, %1, %2" : "=v"(d) : "v"(a), "v"(b)); return d;
}
// wave64 DPP sum -> total in lane 63 -> broadcast via readlane (HW-verified v2-v4)
static __device__ __forceinline__ float wave_red_sum(float ss) {
    asm volatile(
        "s_nop 1\n\t"
        "v_add_f32 %0, %0, %0 row_shr:1 bound_ctrl:0\n\t"
        "s_nop 1\n\t"
        "v_add_f32 %0, %0, %0 row_shr:2 bound_ctrl:0\n\t"
        "s_nop 1\n\t"
        "v_add_f32 %0, %0, %0 row_shr:4 bank_mask:0xe\n\t"
        "s_nop 1\n\t"
        "v_add_f32 %0, %0, %0 row_shr:8 bank_mask:0xc\n\t"
        "s_nop 1\n\t"
        "v_add_f32 %0, %0, %0 row_bcast:15 row_mask:0xa\n\t"
        "s_nop 1\n\t"
        "v_add_f32 %0, %0, %0 row_bcast:31 row_mask:0xc\n\t"
        "s_nop 1"
        : "+v"(ss));
    return __builtin_bit_cast(float, __builtin_amdgcn_readlane(__builtin_bit_cast(int, ss), 63));
}

static __device__ __forceinline__ unsigned short f2bf(float f) {
    __hip_bfloat16 h = __float2bfloat16(f);
    return __builtin_bit_cast(unsigned short, h);
}

// ---------------------------------------------------------------------------
// K0: convert x and W to bf16 (unchanged, proven r1-r4)
// ---------------------------------------------------------------------------
__global__ void k_convert(const float* __restrict__ x, const float* __restrict__ W,
                          unsigned short* __restrict__ xb, unsigned short* __restrict__ wb) {
    const long NX4 = (long)MR * DD / 4;
    const long NW4 = (long)DD * DD / 4;
    const long stride = (long)gridDim.x * blockDim.x;
    for (long j = (long)blockIdx.x * blockDim.x + threadIdx.x; j < NX4 + NW4; j += stride) {
        const float4* src; unsigned short* dst; long o;
        if (j < NX4) { src = (const float4*)x; dst = xb; o = j; }
        else         { src = (const float4*)W; dst = wb; o = j - NX4; }
        float4 v = src[o];
        ushort4 u;
        u.x = f2bf(v.x); u.y = f2bf(v.y); u.z = f2bf(v.z); u.w = f2bf(v.w);
        *(ushort4*)(dst + o * 4) = u;
    }
}

// ---------------------------------------------------------------------------
// K1: Wx = x @ W^T + b  (bf16 MFMA). Unchanged, proven r1-r4.
// ---------------------------------------------------------------------------
__global__ __launch_bounds__(256, 2)
void k_gemm(const unsigned short* __restrict__ A, const unsigned short* __restrict__ Bw,
            const float* __restrict__ bias, float* __restrict__ C) {
    __shared__ char lds[16384];
    char* ldsA = lds;
    char* ldsB = lds + 8192;
    const int tid  = threadIdx.x;
    const int lane = tid & 63;
    const int wid  = tid >> 6;
    const int wm = wid >> 1, wn = wid & 1;
    const size_t arow0 = (size_t)blockIdx.y * 128;
    const int    brow0 = blockIdx.x * 128;

    f32x4_t acc[4][4] = {};

    const int off0 = tid * 16,        row0_ = off0 >> 6, colb0 = off0 & 63;
    const int off1 = 4096 + tid * 16, row1_ = off1 >> 6, colb1 = off1 & 63;

    for (int kk = 0; kk < DD / 32; ++kk) {
        const int kbase = kk * 32;
        __builtin_amdgcn_global_load_lds(
            (gvoid_t*)(A + (arow0 + row0_) * DD + kbase + (colb0 >> 1)),
            (lvoid_t*)(ldsA + off0), 16, 0, 0);
        __builtin_amdgcn_global_load_lds(
            (gvoid_t*)(A + (arow0 + row1_) * DD + kbase + (colb1 >> 1)),
            (lvoid_t*)(ldsA + off1), 16, 0, 0);
        __builtin_amdgcn_global_load_lds(
            (gvoid_t*)(Bw + (size_t)(brow0 + row0_) * DD + kbase + (colb0 >> 1)),
            (lvoid_t*)(ldsB + off0), 16, 0, 0);
        __builtin_amdgcn_global_load_lds(
            (gvoid_t*)(Bw + (size_t)(brow0 + row1_) * DD + kbase + (colb1 >> 1)),
            (lvoid_t*)(ldsB + off1), 16, 0, 0);
        __syncthreads();

        const int ml = lane & 15;
        const int kh = (lane >> 4) * 16;
        bf16x8_t av[4], bv[4];
        #pragma unroll
        for (int i = 0; i < 4; ++i) {
            av[i] = *(const bf16x8_t*)(ldsA + (wm * 64 + i * 16 + ml) * 64 + kh);
            bv[i] = *(const bf16x8_t*)(ldsB + (wn * 64 + i * 16 + ml) * 64 + kh);
        }
        #pragma unroll
        for (int i = 0; i < 4; ++i)
            #pragma unroll
            for (int j = 0; j < 4; ++j)
                acc[i][j] = __builtin_amdgcn_mfma_f32_16x16x32_bf16(av[i], bv[j], acc[i][j], 0, 0, 0);
        __syncthreads();
    }

    const int rq = (lane >> 4) * 4;
    const int cl = lane & 15;
    #pragma unroll
    for (int i = 0; i < 4; ++i) {
        #pragma unroll
        for (int j = 0; j < 4; ++j) {
            const int n = brow0 + wn * 64 + j * 16 + cl;
            const float bb = bias[n];
            #pragma unroll
            for (int q = 0; q < 4; ++q) {
                const size_t m = arow0 + wm * 64 + i * 16 + rq + q;
                C[m * DD + n] = acc[i][j][q] + bb;
            }
        }
    }
}

// ---------------------------------------------------------------------------
// K_GQ: data-only tables for the ss-recurrence (algebra HW-validated in r4):
//   gq_g[b][j] = { j==0 ? 0 : a^2*dot(row j-1, row j),  a^2*||row j||^2 }
// Output lives in d_out dead space (h-rows 1..4). Massively parallel.
// ---------------------------------------------------------------------------
__global__ __launch_bounds__(256)
void k_gq(const float* __restrict__ Wx, const float* __restrict__ la,
          float2* __restrict__ gq_g) {
    const int b = blockIdx.y;
    const int wid = threadIdx.x >> 6, lane = threadIdx.x & 63;
    const int j0 = blockIdx.x * 16 + wid * 4;
    const float alpha = expf(la[0]);
    const float a2 = alpha * alpha;
    const int dof = lane * 4;
    const float* base = Wx + b * DD + dof;

    F4 R[5][4];
    #pragma unroll
    for (int jj = 0; jj < 5; ++jj) {
        const int row = max(j0 - 1 + jj, 0);
        #pragma unroll
        for (int k = 0; k < 4; ++k)
            R[jj][k].v = *(const float4*)(base + (size_t)row * BD + k * 256);
    }
    float red[8];
    #pragma unroll
    for (int sI = 0; sI < 4; ++sI) {
        float g = 0.f, q = 0.f;
        #pragma unroll
        for (int k = 0; k < 4; ++k)
            #pragma unroll
            for (int j = 0; j < 4; ++j) {
                const float w0 = R[sI][k].f[j], w1 = R[sI + 1][k].f[j];
                g = fmaf(w0, w1, g);
                q = fmaf(w1, w1, q);
            }
        red[sI] = g; red[4 + sI] = q;
    }
    #pragma unroll
    for (int m = 1; m < 64; m <<= 1)
        #pragma unroll
        for (int k = 0; k < 8; ++k)
            red[k] += __shfl_xor(red[k], m, 64);
    if (lane == 0) {
        #pragma unroll
        for (int sI = 0; sI < 4; ++sI) {
            const int j = j0 + sI;
            gq_g[(size_t)b * TT + j] =
                make_float2(j == 0 ? 0.f : a2 * red[sI], a2 * red[4 + sI]);
        }
    }
}

// ---------------------------------------------------------------------------
// K2: phase A v6 — single wave per batch row. LDS ring (16 rows) DMA'd via
// global_load_lds; ALL in-loop LDS reads are inline-asm (ds_read_b128/b64),
// invisible to the compiler's waitcnt pass -> no forced vmcnt(0) drains
// (v2's failure mode). Counted waits: refill-then-vmcnt(48) guarantees row
// m+4's DMA complete; lgkmcnt(5) at step top guarantees the 2-step-old
// ds_read batch. Scalar ss-recurrence (validated r4) keeps the wave
// reduction off the critical chain (2-step lead). r-table kept in a
// register lane-slot, flushed to global every 64 steps.
// ---------------------------------------------------------------------------
__global__ __launch_bounds__(64, 1)
void k_phaseA(const float* __restrict__ Wx, const float* __restrict__ h0,
              const float* __restrict__ la, const float2* __restrict__ gq_g,
              float* __restrict__ hout, float* __restrict__ rtab) {
    __shared__ float  ring[RING * DD];   // 64 KB
    __shared__ float2 gqlds[TT];         // 16 KB
    const int b = blockIdx.x;
    const int lane = threadIdx.x;
    const int dof = lane * 4;
    const float alpha = expf(la[0]);
    const float* wbase = Wx + b * DD;

    // ---- preload gq table: 16 KB = 1024 float4 = 16 per lane ----
    {
        const float4* src = (const float4*)(gq_g + (size_t)b * TT);
        float4* dst = (float4*)gqlds;
        #pragma unroll
        for (int i = 0; i < 16; ++i) dst[i * 64 + lane] = src[i * 64 + lane];
    }
    // ---- h0 -> hraw; emit h output row 0 (= h0) ----
    f32x2 hraw[8];
    #pragma unroll
    for (int k = 0; k < 4; ++k) {
        F4 u; u.v = *(const float4*)(h0 + b * DD + k * 256 + dof);
        hraw[2*k] = u.h[0]; hraw[2*k+1] = u.h[1];
        *(float4*)(hout + b * DD + k * 256 + dof) = u.v;
    }
    asm volatile("" :: "v"(hraw[0]), "v"(hraw[1]), "v"(hraw[2]), "v"(hraw[3]),
                       "v"(hraw[4]), "v"(hraw[5]), "v"(hraw[6]), "v"(hraw[7]));
    __builtin_amdgcn_sched_barrier(0);

    // ---- DMA rows 0..15 into the ring ----
    #pragma unroll
    for (int s = 0; s < RING; ++s)
        #pragma unroll
        for (int k = 0; k < 4; ++k)
            __builtin_amdgcn_global_load_lds(
                (gvoid_t*)(wbase + (size_t)s * BD + k * 256 + dof),
                (lvoid_t*)(ring + s * DD + k * 256), 16, 0, 0);

    asm volatile("s_waitcnt vmcnt(48)" ::: "memory");   // rows 0..3 landed
    __builtin_amdgcn_sched_barrier(0);

    // ---- wR[j] <- rows 0..3 ; g2 seeds (asm ds_read) ----
    F4 wR[4][4];
    #pragma unroll
    for (int j = 0; j < 4; ++j)
        #pragma unroll
        for (int k = 0; k < 4; ++k)
            asm volatile("ds_read_b128 %0, %1"
                         : "=v"(wR[j][k].q)
                         : "v"((lds_f*)(ring + j * DD + k * 256 + dof)));
    f32x2 g2[2];
    asm volatile("ds_read_b64 %0, %1" : "=v"(g2[1]) : "v"((lds_f2*)&gqlds[0]));
    asm volatile("ds_read_b64 %0, %1" : "=v"(g2[0]) : "v"((lds_f2*)&gqlds[1]));
    asm volatile("s_waitcnt lgkmcnt(0)" ::: "memory");
    __builtin_amdgcn_sched_barrier(0);

    // ---- prologue reductions: ss0, e for t=1 (hraw0.w1) and t=2 (hraw0.w2) ----
    float ss, ee[2], vr1 = 1.f, vr2 = 1.f;
    {
        f32x2 sa = pk_mul(hraw[0], hraw[0]);
        #pragma unroll
        for (int p = 1; p < 8; ++p) sa = pk_fma(hraw[p], hraw[p], sa);
        ss = wave_red_sum(sa[0] + sa[1]);
        f32x2 da = pk_mul(hraw[0], wR[0][0].h[0]);
        f32x2 ea = pk_mul(hraw[0], wR[1][0].h[0]);
        #pragma unroll
        for (int p = 1; p < 8; ++p) {
            da = pk_fma(hraw[p], wR[0][p>>1].h[p&1], da);
            ea = pk_fma(hraw[p], wR[1][p>>1].h[p&1], ea);
        }
        ee[1] = alpha * wave_red_sum(da[0] + da[1]);   // e for t=1
        ee[0] = alpha * wave_red_sum(ea[0] + ea[1]);   // e for t=2
    }
    float r_keep = 0.f;

    for (int tt = 0; tt < TT; tt += RING) {
        #pragma unroll
        for (int s = 0; s < RING; ++s) {
            const int m = tt + s;            // step index; t = m+1
            const int pe = (s + 1) & 1;      // t parity (tt multiple of 16)

            asm volatile("s_waitcnt lgkmcnt(5)" ::: "memory");
            __builtin_amdgcn_sched_barrier(0);

            // ---- scalar chain: ss_t = vr1*(vr1*ss + 2*(vr2*e_t + G_t)) + Q_t ----
            const float Dp = fmaf(vr2, ee[pe], g2[pe][0]);
            const float u1 = fmaf(vr1, ss, Dp + Dp);
            ss = fmaf(vr1, u1, g2[pe][1]);
            const float rt = __builtin_amdgcn_rsqf(fmaf(ss, INVD, EPSV));
            r_keep = (lane == (m & 63)) ? rt : r_keep;

            // ---- hraw_t = r_{t-1}*hraw_{t-1} + alpha*w_t  (w_t = wR[s&3]) ----
            const f32x2 rr1 = {vr1, vr1};
            const f32x2 aav = {alpha, alpha};
            #pragma unroll
            for (int k = 0; k < 4; ++k) {
                hraw[2*k]   = pk_fma(rr1, hraw[2*k],   pk_mul(aav, wR[s & 3][k].h[0]));
                hraw[2*k+1] = pk_fma(rr1, hraw[2*k+1], pk_mul(aav, wR[s & 3][k].h[1]));
            }

            // ---- e_{t+2} = alpha*dot(hraw_t, w_{t+2})   (w_{t+2} = wR[(s+2)&3]) ----
            {
                const F4* B = wR[(s + 2) & 3];
                f32x2 ea0 = pk_mul(hraw[0], B[0].h[0]);
                f32x2 ea1 = pk_mul(hraw[1], B[0].h[1]);
                f32x2 ea2 = pk_mul(hraw[2], B[1].h[0]);
                f32x2 ea3 = pk_mul(hraw[3], B[1].h[1]);
                ea0 = pk_fma(hraw[4], B[2].h[0], ea0);
                ea1 = pk_fma(hraw[5], B[2].h[1], ea1);
                ea2 = pk_fma(hraw[6], B[3].h[0], ea2);
                ea3 = pk_fma(hraw[7], B[3].h[1], ea3);
                ea0 = pk_add(ea0, ea1); ea2 = pk_add(ea2, ea3); ea0 = pk_add(ea0, ea2);
                ee[pe] = alpha * wave_red_sum(ea0[0] + ea0[1]);
            }

            // ---- refill: DMA row (m+16) into slot s (wrap past end = dummy) ----
            {
                const float* wp = wbase + (size_t)((m + RING) & (TT - 1)) * BD;
                #pragma unroll
                for (int k = 0; k < 4; ++k)
                    __builtin_amdgcn_global_load_lds(
                        (gvoid_t*)(wp + k * 256 + dof),
                        (lvoid_t*)(ring + s * DD + k * 256), 16, 0, 0);
            }

            // row m+4 complete once <=48 vmem ops outstanding (12 newer rows)
            asm volatile("s_waitcnt vmcnt(48)" ::: "memory");
            __builtin_amdgcn_sched_barrier(0);

            // ---- ds_read row m+4 (slot (s+4)&15) -> wR[s&3]; gq for t+2 ----
            #pragma unroll
            for (int k = 0; k < 4; ++k)
                asm volatile("ds_read_b128 %0, %1"
                             : "=v"(wR[s & 3][k].q)
                             : "v"((lds_f*)(ring + ((s + 4) & 15) * DD + k * 256 + dof)));
            asm volatile("ds_read_b64 %0, %1"
                         : "=v"(g2[pe]) : "v"((lds_f2*)&gqlds[(m + 2) & (TT - 1)]));

            vr2 = vr1; vr1 = rt;
        }

        if ((tt & 63) == 48)          // flush 64 r's (one per lane)
            rtab[(size_t)b * TT + (tt - 48) + lane] = r_keep;
        if ((tt & 255) == 240) {      // snapshot h_{tt+16} (multiple of 256)
            float* hp = hout + (size_t)(tt + RING) * BD + b * DD;
            const f32x2 rr0 = {vr1, vr1};
            #pragma unroll
            for (int k = 0; k < 4; ++k) {
                F4 u;
                u.h[0] = pk_mul(rr0, hraw[2*k]);
                u.h[1] = pk_mul(rr0, hraw[2*k+1]);
                *(float4*)(hp + k * 256 + dof) = u.v;
            }
        }
    }

    asm volatile("s_waitcnt vmcnt(0) lgkmcnt(0)" ::: "memory");
}

// ---------------------------------------------------------------------------
// K3: phase B — parallel replay. Unchanged, proven r1-r4.
// ---------------------------------------------------------------------------
__global__ __launch_bounds__(256)
void k_phaseB(float* __restrict__ WxOut, float* __restrict__ hout,
              const float* __restrict__ rtab, const float* __restrict__ la) {
    const int col = blockIdx.x * 256 + threadIdx.x;
    const int c = blockIdx.y;
    const int b = col >> 10;
    const float alpha = expf(la[0]);
    const float* rr = rtab + b * TT;
    float h = hout[(size_t)(c * CH) * BD + col];
    const int t0 = c * CH + 1;
    float w = WxOut[(size_t)(t0 - 1) * BD + col];
    for (int s = 0; s < CH; ++s) {
        const int t = t0 + s;
        float wnext = 0.f;
        if (s + 1 < CH) wnext = WxOut[(size_t)t * BD + col];
        const float r = rr[t - 1];
        const float hraw = fmaf(alpha, w, h);
        const float hn = r * hraw;
        const float sg = 1.0f / (1.0f + __expf(-hn));
        WxOut[(size_t)(t - 1) * BD + col] = hn * hn * sg;
        if ((t & (CH - 1)) != 0 || t == TT)
            hout[(size_t)t * BD + col] = hn;
        h = hn;
        w = wnext;
    }
}

// ---------------------------------------------------------------------------
extern "C" void kernel_launch(void* const* d_in, const int* in_sizes, int n_in,
                              void* d_out, int out_size, void* d_ws, size_t ws_size,
                              hipStream_t stream) {
    (void)in_sizes; (void)n_in; (void)out_size; (void)ws_size;
    const float* x    = (const float*)d_in[0];
    const float* h0   = (const float*)d_in[1];
    const float* W    = (const float*)d_in[2];
    const float* bias = (const float*)d_in[3];
    const float* la   = (const float*)d_in[4];

    float* outr = (float*)d_out;                       // [T][B*D] : Wx, then out
    float* hreg = outr + (size_t)TT * BD;              // [T+1][B*D] : h output
    unsigned short* xb = (unsigned short*)hreg;        // bf16 x (dead space pre-phase-A)
    unsigned short* wb = xb + (size_t)MR * DD;         // bf16 W
    float2* gq_g = (float2*)(hreg + BD);               // 256KB in h-rows 1..4 (dead window)
    float*  rtab = (float*)d_ws;                       // [B][T] = 128KB (proven size)

    k_convert<<<2048, 256, 0, stream>>>(x, W, xb, wb);
    k_gemm<<<dim3(DD / 128, MR / 128), 256, 0, stream>>>(xb, wb, bias, outr);
    k_gq<<<dim3(TT / 16, BB), 256, 0, stream>>>(outr, la, gq_g);
    k_phaseA<<<BB, 64, 0, stream>>>(outr, h0, la, gq_g, hreg, rtab);
    k_phaseB<<<dim3(BD / 256, NCH), 256, 0, stream>>>(outr, hreg, rtab, la);
}

// Round 7
// 542.499 us; speedup vs baseline: 1.3873x; 1.0679x over previous
//
#include <hip/hip_runtime.h>
#include <hip/hip_bf16.h>

#define TT 2048
#define BB 16
#define DD 1024
#define BD (BB*DD)          // 16384 cols per time row
#define MR (TT*BB)          // 32768 GEMM rows
#define EPSV 1e-6f
#define INVD (1.0f/1024.0f)
#define CH 256              // phase-B chunk length
#define NCH (TT/CH)         // 8
#define RING 8              // phase-A register ring depth (rows)

typedef __bf16 bf16x8_t __attribute__((ext_vector_type(8)));
typedef float  f32x4_t  __attribute__((ext_vector_type(4)));
typedef float  f32x2    __attribute__((ext_vector_type(2)));
typedef __attribute__((address_space(1))) void gvoid_t;
typedef __attribute__((address_space(3))) void lvoid_t;
typedef __attribute__((address_space(3))) float2 lds_f2;

union F4 { f32x4_t q; float4 v; f32x2 h[2]; float f[4]; };

static __device__ __forceinline__ f32x2 pk_mul(f32x2 a, f32x2 b) {
    f32x2 d; asm("v_pk_mul_f32 %0, %1, %2" : "=v"(d) : "v"(a), "v"(b)); return d;
}
static __device__ __forceinline__ f32x2 pk_fma(f32x2 a, f32x2 b, f32x2 c) {
    f32x2 d; asm("v_pk_fma_f32 %0, %1, %2, %3" : "=v"(d) : "v"(a), "v"(b), "v"(c)); return d;
}
static __device__ __forceinline__ f32x2 pk_add(f32x2 a, f32x2 b) {
    f32x2 d; asm("v_pk_add_f32 %0, %1, %2" : "=v"(d) : "v"(a), "v"(b)); return d;
}
// wave64 DPP sum -> total in lane 63 -> broadcast via readlane (HW-verified v2-v6)
static __device__ __forceinline__ float wave_red_sum(float ss) {
    asm volatile(
        "s_nop 1\n\t"
        "v_add_f32 %0, %0, %0 row_shr:1 bound_ctrl:0\n\t"
        "s_nop 1\n\t"
        "v_add_f32 %0, %0, %0 row_shr:2 bound_ctrl:0\n\t"
        "s_nop 1\n\t"
        "v_add_f32 %0, %0, %0 row_shr:4 bank_mask:0xe\n\t"
        "s_nop 1\n\t"
        "v_add_f32 %0, %0, %0 row_shr:8 bank_mask:0xc\n\t"
        "s_nop 1\n\t"
        "v_add_f32 %0, %0, %0 row_bcast:15 row_mask:0xa\n\t"
        "s_nop 1\n\t"
        "v_add_f32 %0, %0, %0 row_bcast:31 row_mask:0xc\n\t"
        "s_nop 1"
        : "+v"(ss));
    return __builtin_bit_cast(float, __builtin_amdgcn_readlane(__builtin_bit_cast(int, ss), 63));
}

static __device__ __forceinline__ unsigned short f2bf(float f) {
    __hip_bfloat16 h = __float2bfloat16(f);
    return __builtin_bit_cast(unsigned short, h);
}

// ---------------------------------------------------------------------------
// K0: convert x and W to bf16 (unchanged, proven)
// ---------------------------------------------------------------------------
__global__ void k_convert(const float* __restrict__ x, const float* __restrict__ W,
                          unsigned short* __restrict__ xb, unsigned short* __restrict__ wb) {
    const long NX4 = (long)MR * DD / 4;
    const long NW4 = (long)DD * DD / 4;
    const long stride = (long)gridDim.x * blockDim.x;
    for (long j = (long)blockIdx.x * blockDim.x + threadIdx.x; j < NX4 + NW4; j += stride) {
        const float4* src; unsigned short* dst; long o;
        if (j < NX4) { src = (const float4*)x; dst = xb; o = j; }
        else         { src = (const float4*)W; dst = wb; o = j - NX4; }
        float4 v = src[o];
        ushort4 u;
        u.x = f2bf(v.x); u.y = f2bf(v.y); u.z = f2bf(v.z); u.w = f2bf(v.w);
        *(ushort4*)(dst + o * 4) = u;
    }
}

// ---------------------------------------------------------------------------
// K1: Wx = x @ W^T + b  (bf16 MFMA). Unchanged, proven.
// ---------------------------------------------------------------------------
__global__ __launch_bounds__(256, 2)
void k_gemm(const unsigned short* __restrict__ A, const unsigned short* __restrict__ Bw,
            const float* __restrict__ bias, float* __restrict__ C) {
    __shared__ char lds[16384];
    char* ldsA = lds;
    char* ldsB = lds + 8192;
    const int tid  = threadIdx.x;
    const int lane = tid & 63;
    const int wid  = tid >> 6;
    const int wm = wid >> 1, wn = wid & 1;
    const size_t arow0 = (size_t)blockIdx.y * 128;
    const int    brow0 = blockIdx.x * 128;

    f32x4_t acc[4][4] = {};

    const int off0 = tid * 16,        row0_ = off0 >> 6, colb0 = off0 & 63;
    const int off1 = 4096 + tid * 16, row1_ = off1 >> 6, colb1 = off1 & 63;

    for (int kk = 0; kk < DD / 32; ++kk) {
        const int kbase = kk * 32;
        __builtin_amdgcn_global_load_lds(
            (gvoid_t*)(A + (arow0 + row0_) * DD + kbase + (colb0 >> 1)),
            (lvoid_t*)(ldsA + off0), 16, 0, 0);
        __builtin_amdgcn_global_load_lds(
            (gvoid_t*)(A + (arow0 + row1_) * DD + kbase + (colb1 >> 1)),
            (lvoid_t*)(ldsA + off1), 16, 0, 0);
        __builtin_amdgcn_global_load_lds(
            (gvoid_t*)(Bw + (size_t)(brow0 + row0_) * DD + kbase + (colb0 >> 1)),
            (lvoid_t*)(ldsB + off0), 16, 0, 0);
        __builtin_amdgcn_global_load_lds(
            (gvoid_t*)(Bw + (size_t)(brow0 + row1_) * DD + kbase + (colb1 >> 1)),
            (lvoid_t*)(ldsB + off1), 16, 0, 0);
        __syncthreads();

        const int ml = lane & 15;
        const int kh = (lane >> 4) * 16;
        bf16x8_t av[4], bv[4];
        #pragma unroll
        for (int i = 0; i < 4; ++i) {
            av[i] = *(const bf16x8_t*)(ldsA + (wm * 64 + i * 16 + ml) * 64 + kh);
            bv[i] = *(const bf16x8_t*)(ldsB + (wn * 64 + i * 16 + ml) * 64 + kh);
        }
        #pragma unroll
        for (int i = 0; i < 4; ++i)
            #pragma unroll
            for (int j = 0; j < 4; ++j)
                acc[i][j] = __builtin_amdgcn_mfma_f32_16x16x32_bf16(av[i], bv[j], acc[i][j], 0, 0, 0);
        __syncthreads();
    }

    const int rq = (lane >> 4) * 4;
    const int cl = lane & 15;
    #pragma unroll
    for (int i = 0; i < 4; ++i) {
        #pragma unroll
        for (int j = 0; j < 4; ++j) {
            const int n = brow0 + wn * 64 + j * 16 + cl;
            const float bb = bias[n];
            #pragma unroll
            for (int q = 0; q < 4; ++q) {
                const size_t m = arow0 + wm * 64 + i * 16 + rq + q;
                C[m * DD + n] = acc[i][j][q] + bb;
            }
        }
    }
}

// ---------------------------------------------------------------------------
// K_GQ: data-only tables (unchanged, proven r6):
//   gq_g[b][j] = { j==0 ? 0 : a^2*dot(row j-1, row j),  a^2*||row j||^2 }
// ---------------------------------------------------------------------------
__global__ __launch_bounds__(256)
void k_gq(const float* __restrict__ Wx, const float* __restrict__ la,
          float2* __restrict__ gq_g) {
    const int b = blockIdx.y;
    const int wid = threadIdx.x >> 6, lane = threadIdx.x & 63;
    const int j0 = blockIdx.x * 16 + wid * 4;
    const float alpha = expf(la[0]);
    const float a2 = alpha * alpha;
    const int dof = lane * 4;
    const float* base = Wx + b * DD + dof;

    F4 R[5][4];
    #pragma unroll
    for (int jj = 0; jj < 5; ++jj) {
        const int row = max(j0 - 1 + jj, 0);
        #pragma unroll
        for (int k = 0; k < 4; ++k)
            R[jj][k].v = *(const float4*)(base + (size_t)row * BD + k * 256);
    }
    float red[8];
    #pragma unroll
    for (int sI = 0; sI < 4; ++sI) {
        float g = 0.f, q = 0.f;
        #pragma unroll
        for (int k = 0; k < 4; ++k)
            #pragma unroll
            for (int j = 0; j < 4; ++j) {
                const float w0 = R[sI][k].f[j], w1 = R[sI + 1][k].f[j];
                g = fmaf(w0, w1, g);
                q = fmaf(w1, w1, q);
            }
        red[sI] = g; red[4 + sI] = q;
    }
    #pragma unroll
    for (int m = 1; m < 64; m <<= 1)
        #pragma unroll
        for (int k = 0; k < 8; ++k)
            red[k] += __shfl_xor(red[k], m, 64);
    if (lane == 0) {
        #pragma unroll
        for (int sI = 0; sI < 4; ++sI) {
            const int j = j0 + sI;
            gq_g[(size_t)b * TT + j] =
                make_float2(j == 0 ? 0.f : a2 * red[sI], a2 * red[4 + sI]);
        }
    }
}

// ---------------------------------------------------------------------------
// K2: phase A v7 — v3's proven REGISTER ring (inline-asm global_load_dwordx4,
// no LDS for w, no per-step DMA/ds_read machinery = v6's hidden cost) + the
// r4/r6-validated ss-recurrence (scalar chain ~30cy; e-dot reduction has a
// 2-step slack so DPP cost is issue-only). Per-step LDS = ONE asm ds_read_b64
// (uniform G/Q, prefetched 2 steps ahead, lgkmcnt(1)).
// ---------------------------------------------------------------------------
__global__ __launch_bounds__(64, 1)
void k_phaseA(const float* __restrict__ Wx, const float* __restrict__ h0,
              const float* __restrict__ la, const float2* __restrict__ gq_g,
              float* __restrict__ hout, float* __restrict__ rtab) {
    __shared__ float2 gqlds[TT];         // 16 KB
    const int b = blockIdx.x;
    const int lane = threadIdx.x;
    const int dof = lane * 4;
    const float alpha = expf(la[0]);
    const float* wbase = Wx + b * DD + dof;

    // ---- preload gq table: 1024 float4 = 16 per lane ----
    {
        const float4* src = (const float4*)(gq_g + (size_t)b * TT);
        float4* dst = (float4*)gqlds;
        #pragma unroll
        for (int i = 0; i < 16; ++i) dst[i * 64 + lane] = src[i * 64 + lane];
    }
    // ---- h0 -> hraw; emit h output row 0 (= h0) ----
    f32x2 hraw[8];
    #pragma unroll
    for (int k = 0; k < 4; ++k) {
        F4 u; u.v = *(const float4*)(h0 + b * DD + k * 256 + dof);
        hraw[2*k] = u.h[0]; hraw[2*k+1] = u.h[1];
        *(float4*)(hout + b * DD + k * 256 + dof) = u.v;
    }
    asm volatile("" :: "v"(hraw[0]), "v"(hraw[1]), "v"(hraw[2]), "v"(hraw[3]),
                       "v"(hraw[4]), "v"(hraw[5]), "v"(hraw[6]), "v"(hraw[7]));
    // ensure gq LDS writes are complete before asm ds_reads below
    asm volatile("s_waitcnt lgkmcnt(0)" ::: "memory");
    __builtin_amdgcn_sched_barrier(0);

    // ---- issue the 8-row register ring (rows 0..7 = w_1..w_8) ----
    F4 buf[RING][4];
    #pragma unroll
    for (int s = 0; s < RING; ++s) {
        const float* wp = wbase + (size_t)s * BD;
        #pragma unroll
        for (int k = 0; k < 4; ++k)
            asm volatile("global_load_dwordx4 %0, %1, off"
                         : "=v"(buf[s][k].q) : "v"(wp + k * 256));
    }
    asm volatile("s_waitcnt vmcnt(24)" ::: "memory");   // rows 0,1 landed
    __builtin_amdgcn_sched_barrier(0);

    // ---- prologue: ss0 and e-seeds (validated r6 semantics) ----
    float ss, ee[2], vr1 = 1.f, vr2 = 1.f;
    {
        f32x2 sa = pk_mul(hraw[0], hraw[0]);
        #pragma unroll
        for (int p = 1; p < 8; ++p) sa = pk_fma(hraw[p], hraw[p], sa);
        ss = wave_red_sum(sa[0] + sa[1]);
        f32x2 da = pk_mul(hraw[0], buf[0][0].h[0]);
        f32x2 ea = pk_mul(hraw[0], buf[1][0].h[0]);
        #pragma unroll
        for (int p = 1; p < 8; ++p) {
            da = pk_fma(hraw[p], buf[0][p>>1].h[p&1], da);
            ea = pk_fma(hraw[p], buf[1][p>>1].h[p&1], ea);
        }
        ee[1] = alpha * wave_red_sum(da[0] + da[1]);   // e for t=1 (pe=1)
        ee[0] = alpha * wave_red_sum(ea[0] + ea[1]);   // e for t=2 (pe=0)
    }
    // ---- g2 seeds: {G,Q} for t=1 (pe=1) and t=2 (pe=0), asm ds_read ----
    f32x2 g2v[2];
    asm volatile("ds_read_b64 %0, %1" : "=v"(g2v[1]) : "v"((lds_f2*)&gqlds[0]));
    asm volatile("ds_read_b64 %0, %1" : "=v"(g2v[0]) : "v"((lds_f2*)&gqlds[1]));
    asm volatile("s_waitcnt lgkmcnt(0)" ::: "memory");
    __builtin_amdgcn_sched_barrier(0);

    float r_keep = 0.f;

    for (int tt = 0; tt < TT; tt += RING) {
        #pragma unroll
        for (int s = 0; s < RING; ++s) {
            const int m = tt + s;            // step index; t = m+1
            const int pe = (s + 1) & 1;      // t parity (tt multiple of 8)

            if (s == 0 && (tt & 255) == 0) { // snapshot h_m = vr1*hraw_m
                float* hp = hout + (size_t)tt * BD + b * DD;
                const f32x2 rr0 = {vr1, vr1};
                #pragma unroll
                for (int k = 0; k < 4; ++k) {
                    F4 u;
                    u.h[0] = pk_mul(rr0, hraw[2*k]);
                    u.h[1] = pk_mul(rr0, hraw[2*k+1]);
                    *(float4*)(hp + k * 256 + dof) = u.v;
                }
            }

            // rows m..m+2 complete once <=20 loads outstanding (rows m+3..m+7);
            // stores (snapshots/r-flush) are newer -> only ever over-wait.
            asm volatile("s_waitcnt vmcnt(20)" ::: "memory");
            __builtin_amdgcn_sched_barrier(0);
            // g2 read issued at step m-2 complete once <=1 ds op outstanding
            asm volatile("s_waitcnt lgkmcnt(1)" ::: "memory");
            __builtin_amdgcn_sched_barrier(0);

            // ---- scalar chain: ss_t = vr1*(vr1*ss + 2*(vr2*e_t + G_t)) + Q_t ----
            const float Dp = fmaf(vr2, ee[pe], g2v[pe][0]);
            const float u1 = fmaf(vr1, ss, Dp + Dp);
            ss = fmaf(vr1, u1, g2v[pe][1]);
            const float rt = __builtin_amdgcn_rsqf(fmaf(ss, INVD, EPSV));
            r_keep = (lane == (m & 63)) ? rt : r_keep;

            // ---- hraw_t = r_{t-1}*hraw_{t-1} + alpha*w_t   (w_t = buf[s]) ----
            const f32x2 rr1 = {vr1, vr1};
            const f32x2 aav = {alpha, alpha};
            #pragma unroll
            for (int k = 0; k < 4; ++k) {
                hraw[2*k]   = pk_fma(rr1, hraw[2*k],   pk_mul(aav, buf[s][k].h[0]));
                hraw[2*k+1] = pk_fma(rr1, hraw[2*k+1], pk_mul(aav, buf[s][k].h[1]));
            }

            // ---- e_{t+2} = alpha*dot(hraw_t, w_{t+2})  (w_{t+2} = buf[(s+2)&7]) ----
            {
                const F4* B = buf[(s + 2) & (RING - 1)];
                f32x2 ea0 = pk_mul(hraw[0], B[0].h[0]);
                f32x2 ea1 = pk_mul(hraw[1], B[0].h[1]);
                f32x2 ea2 = pk_mul(hraw[2], B[1].h[0]);
                f32x2 ea3 = pk_mul(hraw[3], B[1].h[1]);
                ea0 = pk_fma(hraw[4], B[2].h[0], ea0);
                ea1 = pk_fma(hraw[5], B[2].h[1], ea1);
                ea2 = pk_fma(hraw[6], B[3].h[0], ea2);
                ea3 = pk_fma(hraw[7], B[3].h[1], ea3);
                ea0 = pk_add(ea0, ea1); ea2 = pk_add(ea2, ea3); ea0 = pk_add(ea0, ea2);
                ee[pe] = alpha * wave_red_sum(ea0[0] + ea0[1]);
            }

            // ---- prefetch {G,Q} for t+2 (consumed at step m+2) ----
            asm volatile("ds_read_b64 %0, %1"
                         : "=v"(g2v[pe]) : "v"((lds_f2*)&gqlds[(m + 2) & (TT - 1)]));

            // ---- refill slot s with row m+8 (wrap past end: dummy, never read) ----
            {
                const float* wp = wbase + (size_t)((m + RING) & (TT - 1)) * BD;
                #pragma unroll
                for (int k = 0; k < 4; ++k)
                    asm volatile("global_load_dwordx4 %0, %1, off"
                                 : "=v"(buf[s][k].q) : "v"(wp + k * 256));
            }

            vr2 = vr1; vr1 = rt;
        }

        if ((tt & 63) == 56)          // flush 64 r's (one per lane)
            rtab[(size_t)b * TT + (tt - 56) + lane] = r_keep;
    }

    asm volatile("s_waitcnt vmcnt(0) lgkmcnt(0)" ::: "memory");
}

// ---------------------------------------------------------------------------
// K3: phase B — parallel replay. Unchanged, proven. (Writes h row TT.)
// ---------------------------------------------------------------------------
__global__ __launch_bounds__(256)
void k_phaseB(float* __restrict__ WxOut, float* __restrict__ hout,
              const float* __restrict__ rtab, const float* __restrict__ la) {
    const int col = blockIdx.x * 256 + threadIdx.x;
    const int c = blockIdx.y;
    const int b = col >> 10;
    const float alpha = expf(la[0]);
    const float* rr = rtab + b * TT;
    float h = hout[(size_t)(c * CH) * BD + col];
    const int t0 = c * CH + 1;
    float w = WxOut[(size_t)(t0 - 1) * BD + col];
    for (int s = 0; s < CH; ++s) {
        const int t = t0 + s;
        float wnext = 0.f;
        if (s + 1 < CH) wnext = WxOut[(size_t)t * BD + col];
        const float r = rr[t - 1];
        const float hraw = fmaf(alpha, w, h);
        const float hn = r * hraw;
        const float sg = 1.0f / (1.0f + __expf(-hn));
        WxOut[(size_t)(t - 1) * BD + col] = hn * hn * sg;
        if ((t & (CH - 1)) != 0 || t == TT)
            hout[(size_t)t * BD + col] = hn;
        h = hn;
        w = wnext;
    }
}

// ---------------------------------------------------------------------------
extern "C" void kernel_launch(void* const* d_in, const int* in_sizes, int n_in,
                              void* d_out, int out_size, void* d_ws, size_t ws_size,
                              hipStream_t stream) {
    (void)in_sizes; (void)n_in; (void)out_size; (void)ws_size;
    const float* x    = (const float*)d_in[0];
    const float* h0   = (const float*)d_in[1];
    const float* W    = (const float*)d_in[2];
    const float* bias = (const float*)d_in[3];
    const float* la   = (const float*)d_in[4];

    float* outr = (float*)d_out;                       // [T][B*D] : Wx, then out
    float* hreg = outr + (size_t)TT * BD;              // [T+1][B*D] : h output
    unsigned short* xb = (unsigned short*)hreg;        // bf16 x (dead space pre-phase-A)
    unsigned short* wb = xb + (size_t)MR * DD;         // bf16 W
    float2* gq_g = (float2*)(hreg + BD);               // 256KB in h-rows 1..4 (dead window)
    float*  rtab = (float*)d_ws;                       // [B][T] = 128KB (proven size)

    k_convert<<<2048, 256, 0, stream>>>(x, W, xb, wb);
    k_gemm<<<dim3(DD / 128, MR / 128), 256, 0, stream>>>(xb, wb, bias, outr);
    k_gq<<<dim3(TT / 16, BB), 256, 0, stream>>>(outr, la, gq_g);
    k_phaseA<<<BB, 64, 0, stream>>>(outr, h0, la, gq_g, hreg, rtab);
    k_phaseB<<<dim3(BD / 256, NCH), 256, 0, stream>>>(outr, hreg, rtab, la);
}